// Round 7
// baseline (600.114 us; speedup 1.0000x reference)
//
#include <hip/hip_runtime.h>
#include <hip/hip_bf16.h>

// MoChA. Round 7: (1) 3-deep register pipeline in mfma_proj/energy_mfma;
// (2) alpha_pre fused into alpha_scan (load q+4 / transcendentals q+2 /
// consume q pipeline); (3) beta stored fp16.
// B=8, Q=128, K=1024, D=512, HM=HC=4, CHUNK=4.

#define NEG_INF (-3.402823466e38f)
#define EPS_MOCHA 1e-6f
#define INV_SCALE 0.04419417382415922f  // 1/sqrt(512)

typedef _Float16 half8 __attribute__((ext_vector_type(8)));
typedef _Float16 half4v __attribute__((ext_vector_type(4)));
typedef float f32x4 __attribute__((ext_vector_type(4)));

// ---------------------------------------------------------------------------
// cvt: fp32 -> fp16, vectorized x4. Grid exactly n/4/256 blocks.
// ---------------------------------------------------------------------------
__global__ __launch_bounds__(256) void cvt_f32_f16(
    const float* __restrict__ in, _Float16* __restrict__ out)
{
    const size_t i = (size_t)blockIdx.x * 256 + threadIdx.x;
    float4 v = *(const float4*)(in + i * 4);
    half4v h = {(_Float16)v.x, (_Float16)v.y, (_Float16)v.z, (_Float16)v.w};
    *(half4v*)(out + i * 4) = h;
}

// ---------------------------------------------------------------------------
// pack_weights: Wt[n][k] = (fp16) W[k][n] for up to 5 weights (grid z).
// ---------------------------------------------------------------------------
__global__ __launch_bounds__(256) void pack_weights(
    const float* __restrict__ Wa, const float* __restrict__ Wb,
    const float* __restrict__ Wc, const float* __restrict__ Wd,
    const float* __restrict__ We, _Float16* __restrict__ out)
{
    const int z = blockIdx.z;
    const float* W = (z == 0) ? Wa : (z == 1) ? Wb : (z == 2) ? Wc
                   : (z == 3) ? Wd : We;
    _Float16* O = out + (size_t)z * 512 * 512;
    const int n0 = blockIdx.x * 64, k0 = blockIdx.y * 64;
    __shared__ float T[64][65];
    const int t = threadIdx.x;
    const int rr = t >> 4, cc = (t & 15) * 4;
#pragma unroll
    for (int r = 0; r < 4; ++r) {
        int k = r * 16 + rr;
        float4 v = *(const float4*)(W + (size_t)(k0 + k) * 512 + n0 + cc);
        T[k][cc + 0] = v.x; T[k][cc + 1] = v.y;
        T[k][cc + 2] = v.z; T[k][cc + 3] = v.w;
    }
    __syncthreads();
    const int nn = t >> 2, kc = (t & 3) * 16;
    _Float16 tmp[16];
#pragma unroll
    for (int i = 0; i < 16; ++i) tmp[i] = (_Float16)T[kc + i][nn];
    _Float16* Op = O + (size_t)(n0 + nn) * 512 + k0 + kc;
    *(half8*)(Op)     = *(half8*)&tmp[0];
    *(half8*)(Op + 8) = *(half8*)&tmp[8];
}

// ---------------------------------------------------------------------------
// MFMA fragment helpers (16x16x32 f16, fp32 acc); k-contiguous rows stride 512.
// ---------------------------------------------------------------------------
__device__ __forceinline__ void load_frags(
    const _Float16* Ap, const _Float16* Bp, int kk, half8 a[4], half8 b[4])
{
#pragma unroll
    for (int t = 0; t < 4; ++t) {
        a[t] = *(const half8*)(Ap + (size_t)t * 16 * 512 + kk);
        b[t] = *(const half8*)(Bp + (size_t)t * 16 * 512 + kk);
    }
}

__device__ __forceinline__ void mfma_step(half8 a[4], half8 b[4], f32x4 acc[4][4])
{
#pragma unroll
    for (int mt = 0; mt < 4; ++mt)
#pragma unroll
        for (int nt = 0; nt < 4; ++nt)
            acc[mt][nt] = __builtin_amdgcn_mfma_f32_16x16x32_f16(
                a[mt], b[nt], acc[mt][nt], 0, 0, 0);
}

// ---------------------------------------------------------------------------
// MFMA projection GEMM: C[m][n] = sum_k A16[m][k]*Wt[n][k] + bias.
// Block 256 = 2x2 waves, tile 128x128, wave 64x64, K=512, 3-deep pipeline
// (loads issue 2 K-steps ahead of use). f16_mask bit g: C stored fp16.
// ---------------------------------------------------------------------------
__global__ __launch_bounds__(256) void mfma_proj(
    const _Float16* __restrict__ A16, const _Float16* __restrict__ Wt_base,
    const float* __restrict__ bias0, void* __restrict__ C0,
    const float* __restrict__ bias1, void* __restrict__ C1,
    const float* __restrict__ bias2, void* __restrict__ C2,
    int f16_mask)
{
    const int tid = threadIdx.x;
    const int lane = tid & 63, wave = tid >> 6;
    const int wm = wave >> 1, wn = wave & 1;
    const int col = lane & 15, quad = lane >> 4;
    const int g = blockIdx.y >> 2, nt128 = blockIdx.y & 3;
    const _Float16* Wt = Wt_base + (size_t)g * 262144;
    const float* bias = (g == 0) ? bias0 : (g == 1) ? bias1 : bias2;
    void*        Cv   = (g == 0) ? C0    : (g == 1) ? C1    : C2;
    const int f16o = (f16_mask >> g) & 1;
    const int m0 = blockIdx.x * 128, n0 = nt128 * 128;

    const _Float16* Ap = A16 + (size_t)(m0 + wm * 64 + col) * 512 + quad * 8;
    const _Float16* Bp = Wt  + (size_t)(n0 + wn * 64 + col) * 512 + quad * 8;

    f32x4 acc[4][4];
#pragma unroll
    for (int mt = 0; mt < 4; ++mt)
#pragma unroll
        for (int nt = 0; nt < 4; ++nt) acc[mt][nt] = (f32x4)0.f;

    half8 ab[3][4], bb[3][4];
    load_frags(Ap, Bp, 0, ab[0], bb[0]);
    load_frags(Ap, Bp, 32, ab[1], bb[1]);
#pragma unroll
    for (int ks = 0; ks < 16; ++ks) {
        const int cur = ks % 3, nxt = (ks + 2) % 3;
        if (ks + 2 < 16)
            load_frags(Ap, Bp, (ks + 2) * 32, ab[nxt], bb[nxt]);
        mfma_step(ab[cur], bb[cur], acc);
    }

    float bnt[4];
#pragma unroll
    for (int nt = 0; nt < 4; ++nt)
        bnt[nt] = bias[n0 + wn * 64 + nt * 16 + col];
#pragma unroll
    for (int mt = 0; mt < 4; ++mt) {
        const int rowb = m0 + wm * 64 + mt * 16 + quad * 4;
#pragma unroll
        for (int nt = 0; nt < 4; ++nt) {
            const int cc = n0 + wn * 64 + nt * 16 + col;
#pragma unroll
            for (int r = 0; r < 4; ++r) {
                float v = acc[mt][nt][r] + bnt[nt];
                if (f16o)
                    ((_Float16*)Cv)[(size_t)(rowb + r) * 512 + cc] = (_Float16)v;
                else
                    ((float*)Cv)[(size_t)(rowb + r) * 512 + cc] = v;
            }
        }
    }
}

// ---------------------------------------------------------------------------
// Energy via MFMA: out[b,h,q,k] = dot_128(Q16, K16) * INV_SCALE (+ r), masked.
// 3-deep pipeline over 4 K-steps. Grid: (kt=8, h=4, b=8).
// ---------------------------------------------------------------------------
__global__ __launch_bounds__(256) void energy_mfma(
    const _Float16* __restrict__ Qp, const _Float16* __restrict__ Kp,
    const int* __restrict__ mask, float* __restrict__ out,
    const float* __restrict__ r_ptr, int use_r)
{
    const int tid = threadIdx.x;
    const int lane = tid & 63, wave = tid >> 6;
    const int wm = wave >> 1, wn = wave & 1;
    const int col = lane & 15, quad = lane >> 4;
    const int kt0 = blockIdx.x * 128;
    const int h = blockIdx.y, b = blockIdx.z;

    const _Float16* Ap = Qp + (size_t)(b * 128 + wm * 64 + col) * 512 + h * 128 + quad * 8;
    const _Float16* Bp = Kp + (size_t)(b * 1024 + kt0 + wn * 64 + col) * 512 + h * 128 + quad * 8;

    f32x4 acc[4][4];
#pragma unroll
    for (int mt = 0; mt < 4; ++mt)
#pragma unroll
        for (int nt = 0; nt < 4; ++nt) acc[mt][nt] = (f32x4)0.f;

    half8 ab[3][4], bb[3][4];
    load_frags(Ap, Bp, 0, ab[0], bb[0]);
    load_frags(Ap, Bp, 32, ab[1], bb[1]);
#pragma unroll
    for (int ks = 0; ks < 4; ++ks) {
        const int cur = ks % 3, nxt = (ks + 2) % 3;
        if (ks + 2 < 4)
            load_frags(Ap, Bp, (ks + 2) * 32, ab[nxt], bb[nxt]);
        mfma_step(ab[cur], bb[cur], acc);
    }

    const float rv = use_r ? r_ptr[0] : 0.f;
#pragma unroll
    for (int mt = 0; mt < 4; ++mt) {
        const int qb = wm * 64 + mt * 16 + quad * 4;
#pragma unroll
        for (int nt = 0; nt < 4; ++nt) {
            const int kc = kt0 + wn * 64 + nt * 16 + col;
#pragma unroll
            for (int r = 0; r < 4; ++r) {
                const int q = qb + r;
                float v = acc[mt][nt][r] * INV_SCALE + rv;
                int mv = mask[((size_t)b * 128 + q) * 1024 + kc];
                out[(((size_t)b * 4 + h) * 128 + q) * 1024 + kc] = mv ? v : NEG_INF;
            }
        }
    }
}

// ---------------------------------------------------------------------------
// alpha_scan (fused): one wave per (b,h), sequential over q, zero barriers.
// 3-stage pipeline: load e row q+4 | transcendentals for row q+2 | consume
// pcp/invcp for row q on the serial chain. Transcendentals never sit on the
// aw dependency chain.
// ---------------------------------------------------------------------------
__device__ __forceinline__ void alpha_transcend(
    const float e[16], int lane, float bp[16], float bi[16])
{
    float p[16], l[16];
#pragma unroll
    for (int i = 0; i < 16; ++i) {
        p[i] = 1.f / (1.f + expf(-e[i]));
        l[i] = logf(fmaxf(1.f - p[i], EPS_MOCHA));
    }
    float incl[16];
    incl[0] = l[0];
#pragma unroll
    for (int i = 1; i < 16; ++i) incl[i] = incl[i - 1] + l[i];
    float total = incl[15];
    float x = total;
#pragma unroll
    for (int off = 1; off < 64; off <<= 1) {
        float y = __shfl_up(x, off, 64);
        if (lane >= off) x += y;
    }
    float base = x - total;  // exclusive prefix across lanes
#pragma unroll
    for (int i = 0; i < 16; ++i) {
        float cl = base + (i ? incl[i - 1] : 0.f);
        float cp = expf(cl);
        bp[i] = p[i] * cp;
        bi[i] = 1.f / fmaxf(cp, EPS_MOCHA);
    }
}

__global__ __launch_bounds__(64) void alpha_scan(
    const float* __restrict__ e_mono, float* __restrict__ alpha)
{
    const int lane = threadIdx.x;
    const int bh = blockIdx.x;
    const float* E = e_mono + (size_t)bh * 131072 + lane * 16;
    float* A = alpha + (size_t)bh * 131072 + lane * 16;

    float eb[4][16];     // e rows q.. loaded 4 ahead
    float bp[2][16], bi[2][16];  // transcendentals computed 2 ahead
#pragma unroll
    for (int s = 0; s < 4; ++s) {
        const float* Eq = E + (size_t)s * 1024;
        *(float4*)&eb[s][0]  = *(const float4*)(Eq);
        *(float4*)&eb[s][4]  = *(const float4*)(Eq + 4);
        *(float4*)&eb[s][8]  = *(const float4*)(Eq + 8);
        *(float4*)&eb[s][12] = *(const float4*)(Eq + 12);
    }
    alpha_transcend(eb[0], lane, bp[0], bi[0]);  // row 0
    alpha_transcend(eb[1], lane, bp[1], bi[1]);  // row 1

    float aw[16];
#pragma unroll
    for (int i = 0; i < 16; ++i) aw[i] = 0.f;
    if (lane == 0) aw[0] = 1.f;

    for (int q4 = 0; q4 < 128; q4 += 4) {
#pragma unroll
        for (int s = 0; s < 4; ++s) {
            const int q = q4 + s;
            const int ps = s & 1;
            float pc[16], ic[16];
#pragma unroll
            for (int i = 0; i < 16; ++i) { pc[i] = bp[ps][i]; ic[i] = bi[ps][i]; }
            if (q + 4 < 128) {  // load e row q+4 into slot s
                const float* Eq = E + (size_t)(q + 4) * 1024;
                *(float4*)&eb[s][0]  = *(const float4*)(Eq);
                *(float4*)&eb[s][4]  = *(const float4*)(Eq + 4);
                *(float4*)&eb[s][8]  = *(const float4*)(Eq + 8);
                *(float4*)&eb[s][12] = *(const float4*)(Eq + 12);
            }
            if (q + 2 < 128)    // transcendentals for row q+2 (loaded 2 ago)
                alpha_transcend(eb[(s + 2) & 3], lane, bp[ps], bi[ps]);

            float incl[16];
            incl[0] = aw[0] * ic[0];
#pragma unroll
            for (int i = 1; i < 16; ++i) incl[i] = incl[i - 1] + aw[i] * ic[i];
            float total = incl[15];
            float x = total;
#pragma unroll
            for (int off = 1; off < 64; off <<= 1) {
                float y = __shfl_up(x, off, 64);
                if (lane >= off) x += y;
            }
            float base = x - total;  // exclusive across lanes
#pragma unroll
            for (int i = 0; i < 16; ++i) aw[i] = pc[i] * (base + incl[i]);

            float* Aq = A + (size_t)q * 1024;
            *(float4*)(Aq)      = *(float4*)&aw[0];
            *(float4*)(Aq + 4)  = *(float4*)&aw[4];
            *(float4*)(Aq + 8)  = *(float4*)&aw[8];
            *(float4*)(Aq + 12) = *(float4*)&aw[12];
        }
    }
}

// ---------------------------------------------------------------------------
// Beta -> fp16. LDS swizzle SW(k)=k+(k>>3). Grid: (q=128, hc=4, b=8).
// ---------------------------------------------------------------------------
#define SW(k) ((k) + ((k) >> 3))

__global__ __launch_bounds__(256) void beta_kernel(
    const float* __restrict__ e_chunk, const float* __restrict__ alpha,
    _Float16* __restrict__ beta)
{
    __shared__ float sm[SW(1023) + 1];
    __shared__ float tm[SW(1027) + 1];
    __shared__ float red[4];
    const int q = blockIdx.x, hc = blockIdx.y, b = blockIdx.z;
    const int tid = threadIdx.x;
    const int lane = tid & 63, wid = tid >> 6;
    const int k4 = tid * 4;

    const float* Erow = e_chunk + (((size_t)b * 4 + hc) * 128 + q) * 1024;
    float4 ev = *(const float4*)(Erow + k4);
    float e[4] = {ev.x, ev.y, ev.z, ev.w};

    float mx = fmaxf(fmaxf(e[0], e[1]), fmaxf(e[2], e[3]));
#pragma unroll
    for (int off = 32; off >= 1; off >>= 1)
        mx = fmaxf(mx, __shfl_xor(mx, off, 64));
    if (lane == 0) red[wid] = mx;
    if (tid < 4) tm[SW(1024 + tid)] = 0.f;
    __syncthreads();
    mx = fmaxf(fmaxf(red[0], red[1]), fmaxf(red[2], red[3]));

    float sx[4];
#pragma unroll
    for (int i = 0; i < 4; ++i) {
        sx[i] = fmaxf(expf(e[i] - mx), 1e-5f);
        sm[SW(k4 + i)] = sx[i];
    }
    __syncthreads();

    float den[4];
#pragma unroll
    for (int i = 0; i < 4; ++i) {
        int k = k4 + i;
        float d = sm[SW(k)];
        if (k >= 1) d += sm[SW(k - 1)];
        if (k >= 2) d += sm[SW(k - 2)];
        if (k >= 3) d += sm[SW(k - 3)];
        den[i] = d;
    }

    for (int hm = 0; hm < 4; ++hm) {
        const float* Arow = alpha + (((size_t)b * 4 + hm) * 128 + q) * 1024;
        float4 av = *(const float4*)(Arow + k4);
        float t[4] = {av.x / den[0], av.y / den[1], av.z / den[2], av.w / den[3]};
#pragma unroll
        for (int i = 0; i < 4; ++i) tm[SW(k4 + i)] = t[i];
        __syncthreads();
        float o[4];
#pragma unroll
        for (int i = 0; i < 4; ++i) {
            int k = k4 + i;
            float ms = tm[SW(k)] + tm[SW(k + 1)] + tm[SW(k + 2)] + tm[SW(k + 3)];
            o[i] = sx[i] * ms;
        }
        _Float16* Brow = beta + (((size_t)b * 16 + hm * 4 + hc) * 128 + q) * 1024;
        half4v hv = {(_Float16)o[0], (_Float16)o[1], (_Float16)o[2], (_Float16)o[3]};
        *(half4v*)(Brow + k4) = hv;
        __syncthreads();
    }
}

// ---------------------------------------------------------------------------
// Context: cv[b,q,h*32+d] = sum_k beta16[b,h,q,k] * V[b,k,h*32+d]
// ---------------------------------------------------------------------------
__global__ __launch_bounds__(256) void context_kernel(
    const _Float16* __restrict__ beta, const float* __restrict__ V,
    float* __restrict__ cv)
{
    __shared__ float bS[32][64];
    __shared__ float vS[32][32];
    const int qh = blockIdx.x, h = blockIdx.y, b = blockIdx.z;
    const int tid = threadIdx.x;
    const int ty = tid >> 3, tx = tid & 7;
    const int q0 = qh * 64;

    const _Float16* Bbase = beta + (((size_t)b * 16 + h) * 128 + q0) * 1024;
    const float* Vbase = V + (size_t)b * 1024 * 512 + h * 32;

    float acc[2][4];
#pragma unroll
    for (int i = 0; i < 2; ++i)
#pragma unroll
        for (int j = 0; j < 4; ++j) acc[i][j] = 0.f;

    for (int k0 = 0; k0 < 1024; k0 += 32) {
        {
            int r = tid >> 2, c = tid & 3;  // r:0..63 rows, c:0..3 (8 k each)
            half8 v = *(const half8*)(Bbase + (size_t)r * 1024 + k0 + c * 8);
#pragma unroll
            for (int j = 0; j < 8; ++j) bS[c * 8 + j][r] = (float)v[j];
        }
        {
            int kk = tid >> 3, c = tid & 7;
            float4 v = *(const float4*)(Vbase + (size_t)(k0 + kk) * 512 + c * 4);
            *(float4*)&vS[kk][c * 4] = v;
        }
        __syncthreads();
#pragma unroll
        for (int kk = 0; kk < 32; ++kk) {
            float a0 = bS[kk][ty * 2], a1 = bS[kk][ty * 2 + 1];
            float bb[4];
            *(float4*)bb = *(const float4*)&vS[kk][tx * 4];
#pragma unroll
            for (int j = 0; j < 4; ++j) {
                acc[0][j] = fmaf(a0, bb[j], acc[0][j]);
                acc[1][j] = fmaf(a1, bb[j], acc[1][j]);
            }
        }
        __syncthreads();
    }
#pragma unroll
    for (int i = 0; i < 2; ++i) {
        float* Cp = cv + ((size_t)b * 128 + q0 + ty * 2 + i) * 512 + h * 32 + tx * 4;
        *(float4*)Cp = make_float4(acc[i][0], acc[i][1], acc[i][2], acc[i][3]);
    }
}

// ---------------------------------------------------------------------------
extern "C" void kernel_launch(void* const* d_in, const int* in_sizes, int n_in,
                              void* d_out, int out_size, void* d_ws, size_t ws_size,
                              hipStream_t stream)
{
    const float* key_x   = (const float*)d_in[0];
    const float* query_x = (const float*)d_in[1];
    const int*   mask    = (const int*)d_in[2];
    const float* wk_m = (const float*)d_in[3];
    const float* bk_m = (const float*)d_in[4];
    const float* wq_m = (const float*)d_in[5];
    const float* bq_m = (const float*)d_in[6];
    const float* r    = (const float*)d_in[7];
    const float* wk_c = (const float*)d_in[8];
    const float* bk_c = (const float*)d_in[9];
    const float* wq_c = (const float*)d_in[10];
    const float* bq_c = (const float*)d_in[11];
    const float* wv   = (const float*)d_in[12];
    const float* bv   = (const float*)d_in[13];
    const float* wo   = (const float*)d_in[14];
    const float* bo   = (const float*)d_in[15];
    float* out = (float*)d_out;

    float* ws = (float*)d_ws;
    _Float16* hws = (_Float16*)d_ws;
    const size_t MEGF = 1024 * 1024;
    // Float-unit layout (fp16 offsets are 2x float offsets):
    //  phase A: K16 f[0,2), Q16 f[4,4.25), Wt5 f[4.5,5.25),
    //           Km16 f[6,8), Kc16 f[8,10), Qm16 f[10,10.125), Qc16 f[10.25,
    //           10.375), e_mono f[11,15), e_chunk f[15,19), V f[19,23)
    //  phase B (alpha): reads e_mono, writes alpha f[23,27)
    //  phase C: beta16 f[0,8) (K16..Km16/Kc16 etc. all dead), cv f[27,27.5)
    //  phase D: Wt_wo f[27.5,27.625), cv16 f[27.75,28). Peak 28 MEGF.
    _Float16* K16   = hws;                          // f 0
    _Float16* Q16   = hws + 8 * MEGF;               // f 4
    _Float16* Wt5   = hws + 9 * MEGF;               // f 4.5
    _Float16* Km16  = hws + 12 * MEGF;              // f 6
    _Float16* Kc16  = hws + 16 * MEGF;              // f 8
    _Float16* Qm16  = hws + 20 * MEGF;              // f 10
    _Float16* Qc16  = hws + 20 * MEGF + MEGF / 2;   // f 10.25
    float* e_mono  = ws + 11 * MEGF;
    float* e_chunk = ws + 15 * MEGF;
    float* V       = ws + 19 * MEGF;
    float* alpha   = ws + 23 * MEGF;
    _Float16* beta16 = hws;                         // f 0 (phase C overlay)
    float* cv      = ws + 27 * MEGF;
    _Float16* Wt_wo = hws + 55 * MEGF;              // f 27.5
    _Float16* cv16  = hws + 55 * MEGF + MEGF / 2;   // f 27.75

    // 0) fp16 packing
    cvt_f32_f16<<<dim3(4096), 256, 0, stream>>>(key_x, K16);
    cvt_f32_f16<<<dim3(512), 256, 0, stream>>>(query_x, Q16);
    pack_weights<<<dim3(8, 8, 5), 256, 0, stream>>>(wk_m, wk_c, wv, wq_m, wq_c, Wt5);
    // 1) key-side projections (M=8192): Km16 (f16), Kc16 (f16), V (f32)
    mfma_proj<<<dim3(64, 12), 256, 0, stream>>>(
        K16, Wt5, bk_m, Km16, bk_c, Kc16, bv, V, 0b011);
    // 2) query-side projections (M=1024): Qm16, Qc16 (f16)
    mfma_proj<<<dim3(8, 8), 256, 0, stream>>>(
        Q16, Wt5 + (size_t)3 * 262144, bq_m, Qm16, bq_c, Qc16, bq_c, Qc16, 0b011);
    // 3) energies via MFMA
    energy_mfma<<<dim3(8, 4, 8), 256, 0, stream>>>(Qm16, Km16, mask, e_mono, r, 1);
    energy_mfma<<<dim3(8, 4, 8), 256, 0, stream>>>(Qc16, Kc16, mask, e_chunk, r, 0);
    // 4) monotonic alpha (fused transcendentals + scan)
    alpha_scan<<<dim3(32), 64, 0, stream>>>(e_mono, alpha);
    // 5) chunkwise beta (fp16 out)
    beta_kernel<<<dim3(128, 4, 8), 256, 0, stream>>>(e_chunk, alpha, beta16);
    // 6) context vectors
    context_kernel<<<dim3(2, 16, 8), 256, 0, stream>>>(beta16, V, cv);
    // 7) output projection via MFMA (M=1024, fp32 out)
    pack_weights<<<dim3(8, 8, 1), 256, 0, stream>>>(wo, wo, wo, wo, wo, Wt_wo);
    cvt_f32_f16<<<dim3(512), 256, 0, stream>>>(cv, cv16);
    mfma_proj<<<dim3(8, 4), 256, 0, stream>>>(
        cv16, Wt_wo, bo, out, bo, out, bo, out, 0b000);
}

// Round 8
// 350.435 us; speedup vs baseline: 1.7125x; 1.7125x over previous
//
#include <hip/hip_runtime.h>
#include <hip/hip_bf16.h>

// MoChA. Round 8: revert R7's alpha fusion (serial-wave transcendentals were
// a 6x regression) -> back to parallel alpha_pre + 4-deep prefetch alpha_scan.
// Keep R7's 3-deep mfma pipeline, fp16 beta, fp16-staged context.
// B=8, Q=128, K=1024, D=512, HM=HC=4, CHUNK=4.

#define NEG_INF (-3.402823466e38f)
#define EPS_MOCHA 1e-6f
#define INV_SCALE 0.04419417382415922f  // 1/sqrt(512)

typedef _Float16 half8 __attribute__((ext_vector_type(8)));
typedef _Float16 half4v __attribute__((ext_vector_type(4)));
typedef float f32x4 __attribute__((ext_vector_type(4)));

// ---------------------------------------------------------------------------
// cvt: fp32 -> fp16, vectorized x4. Grid exactly n/4/256 blocks.
// ---------------------------------------------------------------------------
__global__ __launch_bounds__(256) void cvt_f32_f16(
    const float* __restrict__ in, _Float16* __restrict__ out)
{
    const size_t i = (size_t)blockIdx.x * 256 + threadIdx.x;
    float4 v = *(const float4*)(in + i * 4);
    half4v h = {(_Float16)v.x, (_Float16)v.y, (_Float16)v.z, (_Float16)v.w};
    *(half4v*)(out + i * 4) = h;
}

// ---------------------------------------------------------------------------
// pack_weights: Wt[n][k] = (fp16) W[k][n] for up to 5 weights (grid z).
// ---------------------------------------------------------------------------
__global__ __launch_bounds__(256) void pack_weights(
    const float* __restrict__ Wa, const float* __restrict__ Wb,
    const float* __restrict__ Wc, const float* __restrict__ Wd,
    const float* __restrict__ We, _Float16* __restrict__ out)
{
    const int z = blockIdx.z;
    const float* W = (z == 0) ? Wa : (z == 1) ? Wb : (z == 2) ? Wc
                   : (z == 3) ? Wd : We;
    _Float16* O = out + (size_t)z * 512 * 512;
    const int n0 = blockIdx.x * 64, k0 = blockIdx.y * 64;
    __shared__ float T[64][65];
    const int t = threadIdx.x;
    const int rr = t >> 4, cc = (t & 15) * 4;
#pragma unroll
    for (int r = 0; r < 4; ++r) {
        int k = r * 16 + rr;
        float4 v = *(const float4*)(W + (size_t)(k0 + k) * 512 + n0 + cc);
        T[k][cc + 0] = v.x; T[k][cc + 1] = v.y;
        T[k][cc + 2] = v.z; T[k][cc + 3] = v.w;
    }
    __syncthreads();
    const int nn = t >> 2, kc = (t & 3) * 16;
    _Float16 tmp[16];
#pragma unroll
    for (int i = 0; i < 16; ++i) tmp[i] = (_Float16)T[kc + i][nn];
    _Float16* Op = O + (size_t)(n0 + nn) * 512 + k0 + kc;
    *(half8*)(Op)     = *(half8*)&tmp[0];
    *(half8*)(Op + 8) = *(half8*)&tmp[8];
}

// ---------------------------------------------------------------------------
// MFMA fragment helpers (16x16x32 f16, fp32 acc); k-contiguous rows stride 512.
// ---------------------------------------------------------------------------
__device__ __forceinline__ void load_frags(
    const _Float16* Ap, const _Float16* Bp, int kk, half8 a[4], half8 b[4])
{
#pragma unroll
    for (int t = 0; t < 4; ++t) {
        a[t] = *(const half8*)(Ap + (size_t)t * 16 * 512 + kk);
        b[t] = *(const half8*)(Bp + (size_t)t * 16 * 512 + kk);
    }
}

__device__ __forceinline__ void mfma_step(half8 a[4], half8 b[4], f32x4 acc[4][4])
{
#pragma unroll
    for (int mt = 0; mt < 4; ++mt)
#pragma unroll
        for (int nt = 0; nt < 4; ++nt)
            acc[mt][nt] = __builtin_amdgcn_mfma_f32_16x16x32_f16(
                a[mt], b[nt], acc[mt][nt], 0, 0, 0);
}

// ---------------------------------------------------------------------------
// MFMA projection GEMM: C[m][n] = sum_k A16[m][k]*Wt[n][k] + bias.
// Block 256 = 2x2 waves, tile 128x128, wave 64x64, K=512, 3-deep pipeline.
// f16_mask bit g: C stored fp16.
// ---------------------------------------------------------------------------
__global__ __launch_bounds__(256) void mfma_proj(
    const _Float16* __restrict__ A16, const _Float16* __restrict__ Wt_base,
    const float* __restrict__ bias0, void* __restrict__ C0,
    const float* __restrict__ bias1, void* __restrict__ C1,
    const float* __restrict__ bias2, void* __restrict__ C2,
    int f16_mask)
{
    const int tid = threadIdx.x;
    const int lane = tid & 63, wave = tid >> 6;
    const int wm = wave >> 1, wn = wave & 1;
    const int col = lane & 15, quad = lane >> 4;
    const int g = blockIdx.y >> 2, nt128 = blockIdx.y & 3;
    const _Float16* Wt = Wt_base + (size_t)g * 262144;
    const float* bias = (g == 0) ? bias0 : (g == 1) ? bias1 : bias2;
    void*        Cv   = (g == 0) ? C0    : (g == 1) ? C1    : C2;
    const int f16o = (f16_mask >> g) & 1;
    const int m0 = blockIdx.x * 128, n0 = nt128 * 128;

    const _Float16* Ap = A16 + (size_t)(m0 + wm * 64 + col) * 512 + quad * 8;
    const _Float16* Bp = Wt  + (size_t)(n0 + wn * 64 + col) * 512 + quad * 8;

    f32x4 acc[4][4];
#pragma unroll
    for (int mt = 0; mt < 4; ++mt)
#pragma unroll
        for (int nt = 0; nt < 4; ++nt) acc[mt][nt] = (f32x4)0.f;

    half8 ab[3][4], bb[3][4];
    load_frags(Ap, Bp, 0, ab[0], bb[0]);
    load_frags(Ap, Bp, 32, ab[1], bb[1]);
#pragma unroll
    for (int ks = 0; ks < 16; ++ks) {
        const int cur = ks % 3, nxt = (ks + 2) % 3;
        if (ks + 2 < 16)
            load_frags(Ap, Bp, (ks + 2) * 32, ab[nxt], bb[nxt]);
        mfma_step(ab[cur], bb[cur], acc);
    }

    float bnt[4];
#pragma unroll
    for (int nt = 0; nt < 4; ++nt)
        bnt[nt] = bias[n0 + wn * 64 + nt * 16 + col];
#pragma unroll
    for (int mt = 0; mt < 4; ++mt) {
        const int rowb = m0 + wm * 64 + mt * 16 + quad * 4;
#pragma unroll
        for (int nt = 0; nt < 4; ++nt) {
            const int cc = n0 + wn * 64 + nt * 16 + col;
#pragma unroll
            for (int r = 0; r < 4; ++r) {
                float v = acc[mt][nt][r] + bnt[nt];
                if (f16o)
                    ((_Float16*)Cv)[(size_t)(rowb + r) * 512 + cc] = (_Float16)v;
                else
                    ((float*)Cv)[(size_t)(rowb + r) * 512 + cc] = v;
            }
        }
    }
}

// ---------------------------------------------------------------------------
// Energy via MFMA: out[b,h,q,k] = dot_128(Q16, K16) * INV_SCALE (+ r), masked.
// 3-deep pipeline over 4 K-steps. Grid: (kt=8, h=4, b=8).
// ---------------------------------------------------------------------------
__global__ __launch_bounds__(256) void energy_mfma(
    const _Float16* __restrict__ Qp, const _Float16* __restrict__ Kp,
    const int* __restrict__ mask, float* __restrict__ out,
    const float* __restrict__ r_ptr, int use_r)
{
    const int tid = threadIdx.x;
    const int lane = tid & 63, wave = tid >> 6;
    const int wm = wave >> 1, wn = wave & 1;
    const int col = lane & 15, quad = lane >> 4;
    const int kt0 = blockIdx.x * 128;
    const int h = blockIdx.y, b = blockIdx.z;

    const _Float16* Ap = Qp + (size_t)(b * 128 + wm * 64 + col) * 512 + h * 128 + quad * 8;
    const _Float16* Bp = Kp + (size_t)(b * 1024 + kt0 + wn * 64 + col) * 512 + h * 128 + quad * 8;

    f32x4 acc[4][4];
#pragma unroll
    for (int mt = 0; mt < 4; ++mt)
#pragma unroll
        for (int nt = 0; nt < 4; ++nt) acc[mt][nt] = (f32x4)0.f;

    half8 ab[3][4], bb[3][4];
    load_frags(Ap, Bp, 0, ab[0], bb[0]);
    load_frags(Ap, Bp, 32, ab[1], bb[1]);
#pragma unroll
    for (int ks = 0; ks < 4; ++ks) {
        const int cur = ks % 3, nxt = (ks + 2) % 3;
        if (ks + 2 < 4)
            load_frags(Ap, Bp, (ks + 2) * 32, ab[nxt], bb[nxt]);
        mfma_step(ab[cur], bb[cur], acc);
    }

    const float rv = use_r ? r_ptr[0] : 0.f;
#pragma unroll
    for (int mt = 0; mt < 4; ++mt) {
        const int qb = wm * 64 + mt * 16 + quad * 4;
#pragma unroll
        for (int nt = 0; nt < 4; ++nt) {
            const int kc = kt0 + wn * 64 + nt * 16 + col;
#pragma unroll
            for (int r = 0; r < 4; ++r) {
                const int q = qb + r;
                float v = acc[mt][nt][r] * INV_SCALE + rv;
                int mv = mask[((size_t)b * 128 + q) * 1024 + kc];
                out[(((size_t)b * 4 + h) * 128 + q) * 1024 + kc] = mv ? v : NEG_INF;
            }
        }
    }
}

// ---------------------------------------------------------------------------
// alpha_pre: parallel part of the monotonic recurrence (one wave per row,
// 4096 rows). p=sigmoid(e); cp=exp(excl_cumsum(log(max(1-p,eps))));
// pcp=p*cp (in-place over e_mono); invcp=1/max(cp,eps).
// ---------------------------------------------------------------------------
__global__ __launch_bounds__(256) void alpha_pre(
    const float* __restrict__ e_mono, float* __restrict__ pcp,
    float* __restrict__ invcp)
{
    const int tid = threadIdx.x;
    const int lane = tid & 63;
    const int row = blockIdx.x * 4 + (tid >> 6);
    const float* E = e_mono + (size_t)row * 1024 + lane * 16;

    float e[16];
    *(float4*)&e[0]  = *(const float4*)(E);
    *(float4*)&e[4]  = *(const float4*)(E + 4);
    *(float4*)&e[8]  = *(const float4*)(E + 8);
    *(float4*)&e[12] = *(const float4*)(E + 12);

    float p[16], l[16];
#pragma unroll
    for (int i = 0; i < 16; ++i) {
        p[i] = 1.f / (1.f + expf(-e[i]));
        l[i] = logf(fmaxf(1.f - p[i], EPS_MOCHA));
    }
    float incl[16];
    incl[0] = l[0];
#pragma unroll
    for (int i = 1; i < 16; ++i) incl[i] = incl[i - 1] + l[i];
    float total = incl[15];
    float x = total;
#pragma unroll
    for (int off = 1; off < 64; off <<= 1) {
        float y = __shfl_up(x, off, 64);
        if (lane >= off) x += y;
    }
    float base = x - total;  // exclusive across lanes

    float o1[16], o2[16];
#pragma unroll
    for (int i = 0; i < 16; ++i) {
        float cl = base + (i ? incl[i - 1] : 0.f);
        float cp = expf(cl);
        o1[i] = p[i] * cp;
        o2[i] = 1.f / fmaxf(cp, EPS_MOCHA);
    }
    float* P = pcp + (size_t)row * 1024 + lane * 16;
    float* I = invcp + (size_t)row * 1024 + lane * 16;
    *(float4*)(P)      = *(float4*)&o1[0];
    *(float4*)(P + 4)  = *(float4*)&o1[4];
    *(float4*)(P + 8)  = *(float4*)&o1[8];
    *(float4*)(P + 12) = *(float4*)&o1[12];
    *(float4*)(I)      = *(float4*)&o2[0];
    *(float4*)(I + 4)  = *(float4*)&o2[4];
    *(float4*)(I + 8)  = *(float4*)&o2[8];
    *(float4*)(I + 12) = *(float4*)&o2[12];
}

// ---------------------------------------------------------------------------
// alpha_scan: sequential over q, one wave per (b,h), zero barriers. 4-deep
// software-pipelined prefetch (loads for q+4 issue before the serial chain
// of q). Per q: aw = pcp * inclusive_cumsum_k(aw_prev * invcp).
// ---------------------------------------------------------------------------
__global__ __launch_bounds__(64) void alpha_scan(
    const float* __restrict__ pcp, const float* __restrict__ invcp,
    float* __restrict__ alpha)
{
    const int lane = threadIdx.x;
    const int bh = blockIdx.x;
    const float* P = pcp + (size_t)bh * 131072 + lane * 16;
    const float* I = invcp + (size_t)bh * 131072 + lane * 16;
    float* A = alpha + (size_t)bh * 131072 + lane * 16;

    float bp[4][16], bi[4][16];
#pragma unroll
    for (int s = 0; s < 4; ++s) {
        const float* Pq = P + (size_t)s * 1024;
        const float* Iq = I + (size_t)s * 1024;
        *(float4*)&bp[s][0]  = *(const float4*)(Pq);
        *(float4*)&bp[s][4]  = *(const float4*)(Pq + 4);
        *(float4*)&bp[s][8]  = *(const float4*)(Pq + 8);
        *(float4*)&bp[s][12] = *(const float4*)(Pq + 12);
        *(float4*)&bi[s][0]  = *(const float4*)(Iq);
        *(float4*)&bi[s][4]  = *(const float4*)(Iq + 4);
        *(float4*)&bi[s][8]  = *(const float4*)(Iq + 8);
        *(float4*)&bi[s][12] = *(const float4*)(Iq + 12);
    }

    float aw[16];
#pragma unroll
    for (int i = 0; i < 16; ++i) aw[i] = 0.f;
    if (lane == 0) aw[0] = 1.f;

    for (int q4 = 0; q4 < 128; q4 += 4) {
#pragma unroll
        for (int s = 0; s < 4; ++s) {
            const int q = q4 + s;
            float pc[16], ic[16];
#pragma unroll
            for (int i = 0; i < 16; ++i) { pc[i] = bp[s][i]; ic[i] = bi[s][i]; }
            if (q + 4 < 128) {  // refill slot s for q+4
                const float* Pq = P + (size_t)(q + 4) * 1024;
                const float* Iq = I + (size_t)(q + 4) * 1024;
                *(float4*)&bp[s][0]  = *(const float4*)(Pq);
                *(float4*)&bp[s][4]  = *(const float4*)(Pq + 4);
                *(float4*)&bp[s][8]  = *(const float4*)(Pq + 8);
                *(float4*)&bp[s][12] = *(const float4*)(Pq + 12);
                *(float4*)&bi[s][0]  = *(const float4*)(Iq);
                *(float4*)&bi[s][4]  = *(const float4*)(Iq + 4);
                *(float4*)&bi[s][8]  = *(const float4*)(Iq + 8);
                *(float4*)&bi[s][12] = *(const float4*)(Iq + 12);
            }

            float incl[16];
            incl[0] = aw[0] * ic[0];
#pragma unroll
            for (int i = 1; i < 16; ++i) incl[i] = incl[i - 1] + aw[i] * ic[i];
            float total = incl[15];
            float x = total;
#pragma unroll
            for (int off = 1; off < 64; off <<= 1) {
                float y = __shfl_up(x, off, 64);
                if (lane >= off) x += y;
            }
            float base = x - total;  // exclusive across lanes
#pragma unroll
            for (int i = 0; i < 16; ++i) aw[i] = pc[i] * (base + incl[i]);

            float* Aq = A + (size_t)q * 1024;
            *(float4*)(Aq)      = *(float4*)&aw[0];
            *(float4*)(Aq + 4)  = *(float4*)&aw[4];
            *(float4*)(Aq + 8)  = *(float4*)&aw[8];
            *(float4*)(Aq + 12) = *(float4*)&aw[12];
        }
    }
}

// ---------------------------------------------------------------------------
// Beta -> fp16. LDS swizzle SW(k)=k+(k>>3). Grid: (q=128, hc=4, b=8).
// ---------------------------------------------------------------------------
#define SW(k) ((k) + ((k) >> 3))

__global__ __launch_bounds__(256) void beta_kernel(
    const float* __restrict__ e_chunk, const float* __restrict__ alpha,
    _Float16* __restrict__ beta)
{
    __shared__ float sm[SW(1023) + 1];
    __shared__ float tm[SW(1027) + 1];
    __shared__ float red[4];
    const int q = blockIdx.x, hc = blockIdx.y, b = blockIdx.z;
    const int tid = threadIdx.x;
    const int lane = tid & 63, wid = tid >> 6;
    const int k4 = tid * 4;

    const float* Erow = e_chunk + (((size_t)b * 4 + hc) * 128 + q) * 1024;
    float4 ev = *(const float4*)(Erow + k4);
    float e[4] = {ev.x, ev.y, ev.z, ev.w};

    float mx = fmaxf(fmaxf(e[0], e[1]), fmaxf(e[2], e[3]));
#pragma unroll
    for (int off = 32; off >= 1; off >>= 1)
        mx = fmaxf(mx, __shfl_xor(mx, off, 64));
    if (lane == 0) red[wid] = mx;
    if (tid < 4) tm[SW(1024 + tid)] = 0.f;
    __syncthreads();
    mx = fmaxf(fmaxf(red[0], red[1]), fmaxf(red[2], red[3]));

    float sx[4];
#pragma unroll
    for (int i = 0; i < 4; ++i) {
        sx[i] = fmaxf(expf(e[i] - mx), 1e-5f);
        sm[SW(k4 + i)] = sx[i];
    }
    __syncthreads();

    float den[4];
#pragma unroll
    for (int i = 0; i < 4; ++i) {
        int k = k4 + i;
        float d = sm[SW(k)];
        if (k >= 1) d += sm[SW(k - 1)];
        if (k >= 2) d += sm[SW(k - 2)];
        if (k >= 3) d += sm[SW(k - 3)];
        den[i] = d;
    }

    for (int hm = 0; hm < 4; ++hm) {
        const float* Arow = alpha + (((size_t)b * 4 + hm) * 128 + q) * 1024;
        float4 av = *(const float4*)(Arow + k4);
        float t[4] = {av.x / den[0], av.y / den[1], av.z / den[2], av.w / den[3]};
#pragma unroll
        for (int i = 0; i < 4; ++i) tm[SW(k4 + i)] = t[i];
        __syncthreads();
        float o[4];
#pragma unroll
        for (int i = 0; i < 4; ++i) {
            int k = k4 + i;
            float ms = tm[SW(k)] + tm[SW(k + 1)] + tm[SW(k + 2)] + tm[SW(k + 3)];
            o[i] = sx[i] * ms;
        }
        _Float16* Brow = beta + (((size_t)b * 16 + hm * 4 + hc) * 128 + q) * 1024;
        half4v hv = {(_Float16)o[0], (_Float16)o[1], (_Float16)o[2], (_Float16)o[3]};
        *(half4v*)(Brow + k4) = hv;
        __syncthreads();
    }
}

// ---------------------------------------------------------------------------
// Context: cv[b,q,h*32+d] = sum_k beta16[b,h,q,k] * V[b,k,h*32+d]
// ---------------------------------------------------------------------------
__global__ __launch_bounds__(256) void context_kernel(
    const _Float16* __restrict__ beta, const float* __restrict__ V,
    float* __restrict__ cv)
{
    __shared__ float bS[32][64];
    __shared__ float vS[32][32];
    const int qh = blockIdx.x, h = blockIdx.y, b = blockIdx.z;
    const int tid = threadIdx.x;
    const int ty = tid >> 3, tx = tid & 7;
    const int q0 = qh * 64;

    const _Float16* Bbase = beta + (((size_t)b * 16 + h) * 128 + q0) * 1024;
    const float* Vbase = V + (size_t)b * 1024 * 512 + h * 32;

    float acc[2][4];
#pragma unroll
    for (int i = 0; i < 2; ++i)
#pragma unroll
        for (int j = 0; j < 4; ++j) acc[i][j] = 0.f;

    for (int k0 = 0; k0 < 1024; k0 += 32) {
        {
            int r = tid >> 2, c = tid & 3;
            half8 v = *(const half8*)(Bbase + (size_t)r * 1024 + k0 + c * 8);
#pragma unroll
            for (int j = 0; j < 8; ++j) bS[c * 8 + j][r] = (float)v[j];
        }
        {
            int kk = tid >> 3, c = tid & 7;
            float4 v = *(const float4*)(Vbase + (size_t)(k0 + kk) * 512 + c * 4);
            *(float4*)&vS[kk][c * 4] = v;
        }
        __syncthreads();
#pragma unroll
        for (int kk = 0; kk < 32; ++kk) {
            float a0 = bS[kk][ty * 2], a1 = bS[kk][ty * 2 + 1];
            float bb[4];
            *(float4*)bb = *(const float4*)&vS[kk][tx * 4];
#pragma unroll
            for (int j = 0; j < 4; ++j) {
                acc[0][j] = fmaf(a0, bb[j], acc[0][j]);
                acc[1][j] = fmaf(a1, bb[j], acc[1][j]);
            }
        }
        __syncthreads();
    }
#pragma unroll
    for (int i = 0; i < 2; ++i) {
        float* Cp = cv + ((size_t)b * 128 + q0 + ty * 2 + i) * 512 + h * 32 + tx * 4;
        *(float4*)Cp = make_float4(acc[i][0], acc[i][1], acc[i][2], acc[i][3]);
    }
}

// ---------------------------------------------------------------------------
extern "C" void kernel_launch(void* const* d_in, const int* in_sizes, int n_in,
                              void* d_out, int out_size, void* d_ws, size_t ws_size,
                              hipStream_t stream)
{
    const float* key_x   = (const float*)d_in[0];
    const float* query_x = (const float*)d_in[1];
    const int*   mask    = (const int*)d_in[2];
    const float* wk_m = (const float*)d_in[3];
    const float* bk_m = (const float*)d_in[4];
    const float* wq_m = (const float*)d_in[5];
    const float* bq_m = (const float*)d_in[6];
    const float* r    = (const float*)d_in[7];
    const float* wk_c = (const float*)d_in[8];
    const float* bk_c = (const float*)d_in[9];
    const float* wq_c = (const float*)d_in[10];
    const float* bq_c = (const float*)d_in[11];
    const float* wv   = (const float*)d_in[12];
    const float* bv   = (const float*)d_in[13];
    const float* wo   = (const float*)d_in[14];
    const float* bo   = (const float*)d_in[15];
    float* out = (float*)d_out;

    float* ws = (float*)d_ws;
    _Float16* hws = (_Float16*)d_ws;
    const size_t MEGF = 1024 * 1024;
    // Float-unit layout (fp16 offsets are 2x float offsets):
    //  phase A: K16 f[0,2), Q16 f[4,4.25), Wt5 f[4.5,5.25),
    //           Km16 f[6,8), Kc16 f[8,10), Qm16 f[10,10.125),
    //           Qc16 f[10.25,10.375), e_mono f[11,15), e_chunk f[15,19),
    //           V f[19,23)
    //  phase B (alpha): pcp = e_mono in-place; invcp f[0,4) (K16/Q16 dead);
    //           alpha f[23,27)
    //  phase C: beta16 f[0,8) (invcp/Km16/Kc16 dead after alpha_scan/energy),
    //           cv f[27,27.5)
    //  phase D: Wt_wo f[27.5,27.625), cv16 f[27.75,28). Peak 28 MEGF.
    _Float16* K16   = hws;                          // f 0
    _Float16* Q16   = hws + 8 * MEGF;               // f 4
    _Float16* Wt5   = hws + 9 * MEGF;               // f 4.5
    _Float16* Km16  = hws + 12 * MEGF;              // f 6
    _Float16* Kc16  = hws + 16 * MEGF;              // f 8
    _Float16* Qm16  = hws + 20 * MEGF;              // f 10
    _Float16* Qc16  = hws + 20 * MEGF + MEGF / 2;   // f 10.25
    float* e_mono  = ws + 11 * MEGF;
    float* pcp     = e_mono;                        // in-place
    float* invcp   = ws;                            // f 0 (over dead K16/Q16)
    float* e_chunk = ws + 15 * MEGF;
    float* V       = ws + 19 * MEGF;
    float* alpha   = ws + 23 * MEGF;
    _Float16* beta16 = hws;                         // f 0 (phase C overlay)
    float* cv      = ws + 27 * MEGF;
    _Float16* Wt_wo = hws + 55 * MEGF;              // f 27.5
    _Float16* cv16  = hws + 55 * MEGF + MEGF / 2;   // f 27.75

    // 0) fp16 packing
    cvt_f32_f16<<<dim3(4096), 256, 0, stream>>>(key_x, K16);
    cvt_f32_f16<<<dim3(512), 256, 0, stream>>>(query_x, Q16);
    pack_weights<<<dim3(8, 8, 5), 256, 0, stream>>>(wk_m, wk_c, wv, wq_m, wq_c, Wt5);
    // 1) key-side projections (M=8192): Km16 (f16), Kc16 (f16), V (f32)
    mfma_proj<<<dim3(64, 12), 256, 0, stream>>>(
        K16, Wt5, bk_m, Km16, bk_c, Kc16, bv, V, 0b011);
    // 2) query-side projections (M=1024): Qm16, Qc16 (f16)
    mfma_proj<<<dim3(8, 8), 256, 0, stream>>>(
        Q16, Wt5 + (size_t)3 * 262144, bq_m, Qm16, bq_c, Qc16, bq_c, Qc16, 0b011);
    // 3) energies via MFMA
    energy_mfma<<<dim3(8, 4, 8), 256, 0, stream>>>(Qm16, Km16, mask, e_mono, r, 1);
    energy_mfma<<<dim3(8, 4, 8), 256, 0, stream>>>(Qc16, Kc16, mask, e_chunk, r, 0);
    // 4) monotonic alpha: parallel transcendentals + 4-deep prefetch scan
    alpha_pre<<<dim3(1024), 256, 0, stream>>>(e_mono, pcp, invcp);
    alpha_scan<<<dim3(32), 64, 0, stream>>>(pcp, invcp, alpha);
    // 5) chunkwise beta (fp16 out)
    beta_kernel<<<dim3(128, 4, 8), 256, 0, stream>>>(e_chunk, alpha, beta16);
    // 6) context vectors
    context_kernel<<<dim3(2, 16, 8), 256, 0, stream>>>(beta16, V, cv);
    // 7) output projection via MFMA (M=1024, fp32 out)
    pack_weights<<<dim3(8, 8, 1), 256, 0, stream>>>(wo, wo, wo, wo, wo, Wt_wo);
    cvt_f32_f16<<<dim3(512), 256, 0, stream>>>(cv, cv16);
    mfma_proj<<<dim3(8, 4), 256, 0, stream>>>(
        cv16, Wt_wo, bo, out, bo, out, bo, out, 0b000);
}